// Round 1
// baseline (113.864 us; speedup 1.0000x reference)
//
#include <hip/hip_runtime.h>
#include <math.h>

#define B_N 384
#define D_DIM 512
#define L_N 40
#define LOG2E100 144.26950408889634f  // 100 * log2(e)

// ---------------- Kernel 1: row L2-normalize ----------------
__global__ __launch_bounds__(64) void k_norm(const float* __restrict__ x,
                                             float* __restrict__ xn) {
    int r = blockIdx.x;
    int lane = threadIdx.x;
    const float* row = x + r * D_DIM;
    float ss = 0.f;
#pragma unroll
    for (int i = 0; i < D_DIM / 64; ++i) {
        float v = row[lane + i * 64];
        ss = fmaf(v, v, ss);
    }
#pragma unroll
    for (int off = 32; off; off >>= 1) ss += __shfl_xor(ss, off);
    float denom = fmaxf(sqrtf(ss), 1e-12f);
    float inv = 1.0f / denom;
    float* orow = xn + r * D_DIM;
#pragma unroll
    for (int i = 0; i < D_DIM / 64; ++i)
        orow[lane + i * 64] = row[lane + i * 64] * inv;
}

// ---------------- Kernel 2: label metadata ----------------
// posw[k][l] = (float)labels[k][l]; w[l] = valid/(max(cnt,1)*B*n_valid);
// out[0] = term0 (1 if any valid label else 0)
__global__ __launch_bounds__(384) void k_meta(const int* __restrict__ labels,
                                              float* __restrict__ posw,
                                              float* __restrict__ w,
                                              float* __restrict__ out) {
    __shared__ float scnt[L_N];
    __shared__ float snv;
    int t = threadIdx.x;
#pragma unroll
    for (int l = 0; l < L_N; ++l) posw[t * L_N + l] = (float)labels[t * L_N + l];
    if (t < L_N) {
        int c = 0;
        for (int k = 0; k < B_N; ++k) c += labels[k * L_N + t];
        scnt[t] = (float)c;
    }
    __syncthreads();
    if (t == 0) {
        float nv = 0.f;
        for (int l = 0; l < L_N; ++l) nv += (scnt[l] > 1.0f) ? 1.f : 0.f;
        snv = fmaxf(nv, 1.f);
        out[0] = (nv > 0.f) ? 1.0f : 0.0f;  // term0
    }
    __syncthreads();
    if (t < L_N) {
        float cnt = scnt[t];
        bool valid = cnt > 1.0f;
        w[t] = valid ? 1.0f / (fmaxf(cnt, 1.f) * (float)B_N * snv) : 0.0f;
    }
}

// ---------------- Kernel 3: sim = xn @ xn^T (fp32, tiled) ----------------
#define TK 64
__global__ __launch_bounds__(256) void k_sim(const float* __restrict__ xn,
                                             float* __restrict__ sim) {
    __shared__ float As[16][TK + 1];
    __shared__ float Bs[16][TK + 1];
    int tx = threadIdx.x, ty = threadIdx.y;
    int i0 = blockIdx.y * 16, j0 = blockIdx.x * 16;
    int tid = ty * 16 + tx;
    int lr = tid >> 4;          // 0..15
    int lc = (tid & 15) * 4;    // 0..60
    float c = 0.f;
    for (int kk = 0; kk < D_DIM; kk += TK) {
        float4 va = *(const float4*)(xn + (i0 + lr) * D_DIM + kk + lc);
        As[lr][lc] = va.x; As[lr][lc + 1] = va.y; As[lr][lc + 2] = va.z; As[lr][lc + 3] = va.w;
        float4 vb = *(const float4*)(xn + (j0 + lr) * D_DIM + kk + lc);
        Bs[lr][lc] = vb.x; Bs[lr][lc + 1] = vb.y; Bs[lr][lc + 2] = vb.z; Bs[lr][lc + 3] = vb.w;
        __syncthreads();
#pragma unroll
        for (int k = 0; k < TK; ++k) c = fmaf(As[ty][k], Bs[tx][k], c);
        __syncthreads();
    }
    sim[(i0 + ty) * B_N + (j0 + tx)] = c;
}

// ---------------- Kernel 4: main pair loop ----------------
// One wave (64 threads) per (q, j-chunk of 64). Inner loop over k (384):
//   sg = 1/(1+exp2((t_j - s_k)*C)); accall += sg; acc[l] += pos[k][l]*sg
// Epilogue: contrib_j = (1/(0.5+accall)) * sum_l wq[l]*pos[j][l]*(0.5+acc[l])
// out -= sum contrib
__global__ __launch_bounds__(64) void k_main(const float* __restrict__ sim,
                                             const float* __restrict__ posw,
                                             const float* __restrict__ w,
                                             float* __restrict__ out) {
    __shared__ float simqC[B_N];
    __shared__ float wq[L_N];
    int q = blockIdx.x / 6;
    int j0 = (blockIdx.x % 6) * 64;
    int lane = threadIdx.x;
    for (int i = lane; i < B_N; i += 64) simqC[i] = sim[q * B_N + i] * LOG2E100;
    if (lane < L_N) wq[lane] = w[lane] * posw[q * L_N + lane];
    __syncthreads();

    int j = j0 + lane;
    float tc = simqC[j];
    float acc[L_N];
#pragma unroll
    for (int l = 0; l < L_N; ++l) acc[l] = 0.f;
    float accall = 0.f;

    for (int k = 0; k < B_N; ++k) {
        float arg = tc - simqC[k];
        float e = __builtin_amdgcn_exp2f(arg);
        float sg = __builtin_amdgcn_rcpf(1.0f + e);
        accall += sg;
        const float* pk = posw + k * L_N;  // wave-uniform address -> s_load
#pragma unroll
        for (int l = 0; l < L_N; ++l) acc[l] = fmaf(pk[l], sg, acc[l]);
    }

    float W = __builtin_amdgcn_rcpf(0.5f + accall);
    float s = 0.f;
    const float* pj = posw + j * L_N;
#pragma unroll
    for (int l = 0; l < L_N; ++l) s += wq[l] * pj[l] * (0.5f + acc[l]);
    float contrib = W * s;
#pragma unroll
    for (int off = 32; off; off >>= 1) contrib += __shfl_down(contrib, off);
    if (lane == 0) atomicAdd(out, -contrib);
}

// ---------------- launch ----------------
extern "C" void kernel_launch(void* const* d_in, const int* in_sizes, int n_in,
                              void* d_out, int out_size, void* d_ws, size_t ws_size,
                              hipStream_t stream) {
    const float* emb = (const float*)d_in[0];
    const int* labels = (const int*)d_in[1];
    float* out = (float*)d_out;

    // ws layout (floats)
    float* xn = (float*)d_ws;                    // 384*512
    float* sim = xn + B_N * D_DIM;               // 384*384
    float* posw = sim + B_N * B_N;               // 384*40
    float* w = posw + B_N * L_N;                 // 40

    k_norm<<<dim3(B_N), dim3(64), 0, stream>>>(emb, xn);
    k_meta<<<dim3(1), dim3(B_N), 0, stream>>>(labels, posw, w, out);
    k_sim<<<dim3(B_N / 16, B_N / 16), dim3(16, 16), 0, stream>>>(xn, sim);
    k_main<<<dim3(B_N * 6), dim3(64), 0, stream>>>(sim, posw, w, out);
}

// Round 2
// 59.354 us; speedup vs baseline: 1.9184x; 1.9184x over previous
//
#include <hip/hip_runtime.h>
#include <hip/hip_bf16.h>
#include <math.h>

#define BN 384
#define DD 512
#define LN 40
#define CLOG 144.26950408889634f   // 100 * log2(e)

typedef __attribute__((ext_vector_type(8))) short short8;
typedef __attribute__((ext_vector_type(4))) float f32x4;
typedef unsigned short u16;

static __device__ __forceinline__ short bfbits(float f) {
    __hip_bfloat16 h = __float2bfloat16(f);
    return __builtin_bit_cast(short, h);
}

// ---------------- Kernel 1: normalize + bf16 hi/lo split ----------------
__global__ __launch_bounds__(64) void k_norm(const float* __restrict__ emb,
                                             u16* __restrict__ xh,
                                             u16* __restrict__ xl) {
    int r = blockIdx.x;
    int lane = threadIdx.x;
    const float* row = emb + (size_t)r * DD;
    f32x4 v0 = *(const f32x4*)(row + lane * 8);
    f32x4 v1 = *(const f32x4*)(row + lane * 8 + 4);
    float ss = 0.f;
#pragma unroll
    for (int e = 0; e < 4; ++e) { ss = fmaf(v0[e], v0[e], ss); ss = fmaf(v1[e], v1[e], ss); }
#pragma unroll
    for (int off = 32; off; off >>= 1) ss += __shfl_xor(ss, off);
    float inv = 1.0f / fmaxf(sqrtf(ss), 1e-12f);
    short8 hv, lv;
#pragma unroll
    for (int e = 0; e < 8; ++e) {
        float v = (e < 4 ? v0[e] : v1[e - 4]) * inv;
        __hip_bfloat16 hb = __float2bfloat16(v);
        float hf = __bfloat162float(hb);
        hv[e] = __builtin_bit_cast(short, hb);
        lv[e] = bfbits(v - hf);
    }
    *(short8*)(xh + (size_t)r * DD + lane * 8) = hv;
    *(short8*)(xl + (size_t)r * DD + lane * 8) = lv;
}

// ---------------- Kernel 2: label metadata + fragment-ordered P ----------------
// w[l] (48, zero-padded), term0, pfrag[kstep][ltile][lane][8] bf16 (B-fragment order)
__global__ __launch_bounds__(256) void k_meta(const int* __restrict__ labels,
                                              float* __restrict__ w,
                                              float* __restrict__ term0,
                                              u16* __restrict__ pfrag) {
    __shared__ int part[240];
    __shared__ float cnt_s[LN];
    __shared__ float nv_s;
    int tid = threadIdx.x;
    if (tid < 240) {
        int l = tid % LN, seg = tid / LN;   // 6 segments x 64 rows
        int c = 0;
        for (int k = seg * 64; k < seg * 64 + 64; ++k) c += labels[k * LN + l];
        part[tid] = c;
    }
    __syncthreads();
    if (tid < LN) {
        int c = 0;
#pragma unroll
        for (int s = 0; s < 6; ++s) c += part[s * LN + tid];
        cnt_s[tid] = (float)c;
    }
    __syncthreads();
    if (tid == 0) {
        float nv = 0.f;
        for (int l = 0; l < LN; ++l) nv += (cnt_s[l] > 1.0f) ? 1.f : 0.f;
        term0[0] = (nv > 0.f) ? 1.0f : 0.0f;
        nv_s = fmaxf(nv, 1.0f);
    }
    __syncthreads();
    if (tid < 48)
        w[tid] = (tid < LN && cnt_s[tid] > 1.0f)
                     ? 1.0f / (cnt_s[tid] * (float)BN * nv_s) : 0.0f;
    // P_ext in B-fragment order: unit u = (ks*3 + lt)*64 + lane, 8 bf16 each
    for (int u = tid; u < 12 * 3 * 64; u += 256) {
        int ks = u / 192, r = u % 192;
        int lt = r >> 6, ln = r & 63;
        int kb = ks * 32 + ((ln >> 4) << 3);
        short8 vals;
#pragma unroll
        for (int e = 0; e < 8; ++e) {
            int k = kb + e;
            int l = lt * 16 + (ln & 15);
            short bv = 0;
            if (l < LN) bv = labels[k * LN + l] ? (short)0x3F80 : (short)0;
            else if (l == LN) bv = (short)0x3F80;   // ones column -> rk_all
            vals[e] = bv;
        }
        *(short8*)(pfrag + (size_t)u * 8) = vals;
    }
}

// ---------------- Kernel 3: sim = X X^T via split-bf16 MFMA ----------------
// X = Xh + Xl; sim = Xh.Xh^T + Xh.Xl^T + Xl.Xh^T (lo*lo dropped, ~2^-18)
__global__ __launch_bounds__(256) void k_sim(const u16* __restrict__ xh,
                                             const u16* __restrict__ xl,
                                             float* __restrict__ sim) {
    int lane = threadIdx.x & 63;
    int wv = threadIdx.x >> 6;
    int i0 = blockIdx.y * 64 + wv * 16;
    int j0 = blockIdx.x * 64;
    f32x4 acc[4];
#pragma unroll
    for (int jt = 0; jt < 4; ++jt) acc[jt] = (f32x4){0.f, 0.f, 0.f, 0.f};
    int r_i = i0 + (lane & 15);
    for (int ks = 0; ks < DD / 32; ++ks) {
        int kb = ks * 32 + ((lane >> 4) << 3);
        short8 ah = *(const short8*)(xh + (size_t)r_i * DD + kb);
        short8 al = *(const short8*)(xl + (size_t)r_i * DD + kb);
#pragma unroll
        for (int jt = 0; jt < 4; ++jt) {
            int r_j = j0 + jt * 16 + (lane & 15);
            short8 bh = *(const short8*)(xh + (size_t)r_j * DD + kb);
            short8 bl = *(const short8*)(xl + (size_t)r_j * DD + kb);
            acc[jt] = __builtin_amdgcn_mfma_f32_16x16x32_bf16(ah, bh, acc[jt], 0, 0, 0);
            acc[jt] = __builtin_amdgcn_mfma_f32_16x16x32_bf16(ah, bl, acc[jt], 0, 0, 0);
            acc[jt] = __builtin_amdgcn_mfma_f32_16x16x32_bf16(al, bh, acc[jt], 0, 0, 0);
        }
    }
    int rbase = i0 + ((lane >> 4) << 2);
#pragma unroll
    for (int jt = 0; jt < 4; ++jt)
#pragma unroll
        for (int rg = 0; rg < 4; ++rg)
            sim[(size_t)(rbase + rg) * BN + j0 + jt * 16 + (lane & 15)] = acc[jt][rg];
}

// ---------------- Kernel 4: main — sg gen + MFMA rank accumulation ----------------
// WG = (q, j-half). 4 waves x 48 j-rows. ACC[j,l] = sum_k sg[j,k] * P_ext[k,l].
__global__ __launch_bounds__(256) void k_main(const float* __restrict__ sim,
                                              const int* __restrict__ labels,
                                              const float* __restrict__ w,
                                              const u16* __restrict__ pfrag,
                                              float* __restrict__ partials) {
    __shared__ float a_lds[BN];
    __shared__ float F_lds[BN];
    __shared__ float wql[48];
    __shared__ float red[16];
    __shared__ float m_sh;
    __shared__ float wpart[4];
    int tid = threadIdx.x;
    int bid = blockIdx.x;
    int q = bid >> 1;
    int lane = tid & 63;
    int wv = tid >> 6;

    // a = C*sim[q,:]; find max/min for centering
    float mx = -3.0e38f, mn = 3.0e38f;
    for (int i = tid; i < BN; i += 256) {
        float a = sim[(size_t)q * BN + i] * CLOG;
        a_lds[i] = a;
        mx = fmaxf(mx, a); mn = fminf(mn, a);
    }
#pragma unroll
    for (int off = 32; off; off >>= 1) {
        mx = fmaxf(mx, __shfl_xor(mx, off));
        mn = fminf(mn, __shfl_xor(mn, off));
    }
    if (lane == 0) { red[wv] = mx; red[8 + wv] = mn; }
    __syncthreads();
    if (tid == 0) {
        float M = fmaxf(fmaxf(red[0], red[1]), fmaxf(red[2], red[3]));
        float N = fminf(fminf(red[8], red[9]), fminf(red[10], red[11]));
        m_sh = 0.5f * (M + N);
    }
    if (tid < 48) wql[tid] = (tid < LN) ? w[tid] * (float)labels[q * LN + tid] : 0.0f;
    __syncthreads();
    float m = m_sh;
    for (int i = tid; i < BN; i += 256) {
        float d = fminf(fmaxf(m - a_lds[i], -126.f), 126.f);
        F_lds[i] = __builtin_amdgcn_exp2f(d);
    }
    __syncthreads();

    int jbase = (bid & 1) * 192 + wv * 48;
    float E[3];
#pragma unroll
    for (int t = 0; t < 3; ++t) {
        float aj = a_lds[jbase + t * 16 + (lane & 15)];
        E[t] = __builtin_amdgcn_exp2f(fminf(fmaxf(aj - m, -126.f), 126.f));
    }

    f32x4 acc[3][3];
#pragma unroll
    for (int t = 0; t < 3; ++t)
#pragma unroll
        for (int lt = 0; lt < 3; ++lt) acc[t][lt] = (f32x4){0.f, 0.f, 0.f, 0.f};

    int kg = (lane >> 4) << 3;
    for (int ks = 0; ks < 12; ++ks) {
        const u16* pb = pfrag + ((size_t)(ks * 3) * 64 + lane) * 8;
        short8 bf0 = *(const short8*)(pb);
        short8 bf1 = *(const short8*)(pb + 64 * 8);
        short8 bf2 = *(const short8*)(pb + 128 * 8);
        f32x4 fa = *(const f32x4*)&F_lds[ks * 32 + kg];
        f32x4 fb = *(const f32x4*)&F_lds[ks * 32 + kg + 4];
#pragma unroll
        for (int t = 0; t < 3; ++t) {
            float e = E[t];
            short8 af;
#pragma unroll
            for (int u = 0; u < 4; ++u) {
                float p0 = fmaf(e, fa[u], 1.0f);
                float p1 = fmaf(e, fb[u], 1.0f);
                af[u] = bfbits(__builtin_amdgcn_rcpf(p0));
                af[u + 4] = bfbits(__builtin_amdgcn_rcpf(p1));
            }
            acc[t][0] = __builtin_amdgcn_mfma_f32_16x16x32_bf16(af, bf0, acc[t][0], 0, 0, 0);
            acc[t][1] = __builtin_amdgcn_mfma_f32_16x16x32_bf16(af, bf1, acc[t][1], 0, 0, 0);
            acc[t][2] = __builtin_amdgcn_mfma_f32_16x16x32_bf16(af, bf2, acc[t][2], 0, 0, 0);
        }
    }

    // epilogue: part += W_j * sum_l wql[l]*pos[j,l]*(0.5+ACC[j,l])
    float part = 0.f;
#pragma unroll
    for (int t = 0; t < 3; ++t) {
#pragma unroll
        for (int rg = 0; rg < 4; ++rg) {
            int j = jbase + t * 16 + ((lane >> 4) << 2) + rg;
            float av = __shfl(acc[t][2][rg], (lane & 48) | 8);   // l=40 ones column
            float W = __builtin_amdgcn_rcpf(0.5f + av);
            float sv = 0.f;
#pragma unroll
            for (int lt = 0; lt < 3; ++lt) {
                int l = lt * 16 + (lane & 15);
                float pj = (l < LN) ? (float)labels[j * LN + l] : 0.f;
                sv = fmaf(wql[l] * pj, 0.5f + acc[t][lt][rg], sv);
            }
            part = fmaf(W, sv, part);
        }
    }
#pragma unroll
    for (int off = 32; off; off >>= 1) part += __shfl_xor(part, off);
    if (lane == 0) wpart[wv] = part;
    __syncthreads();
    if (tid == 0) partials[bid] = (wpart[0] + wpart[1]) + (wpart[2] + wpart[3]);
}

// ---------------- Kernel 5: deterministic final reduce ----------------
__global__ __launch_bounds__(64) void k_final(const float* __restrict__ partials,
                                              const float* __restrict__ term0,
                                              float* __restrict__ out) {
    int lane = threadIdx.x;
    float s = 0.f;
    for (int i = lane; i < 768; i += 64) s += partials[i];
#pragma unroll
    for (int off = 32; off; off >>= 1) s += __shfl_xor(s, off);
    if (lane == 0) out[0] = term0[0] - s;
}

// ---------------- launch ----------------
extern "C" void kernel_launch(void* const* d_in, const int* in_sizes, int n_in,
                              void* d_out, int out_size, void* d_ws, size_t ws_size,
                              hipStream_t stream) {
    const float* emb = (const float*)d_in[0];
    const int* labels = (const int*)d_in[1];
    float* out = (float*)d_out;

    char* ws = (char*)d_ws;
    u16* xh      = (u16*)(ws);                    //  393,216 B
    u16* xl      = (u16*)(ws + 393216);           //  393,216 B
    float* sim   = (float*)(ws + 786432);         //  589,824 B
    u16* pfrag   = (u16*)(ws + 1376256);          //   36,864 B
    float* w     = (float*)(ws + 1413120);        //      192 B
    float* term0 = (float*)(ws + 1413312);        //       64 B
    float* parts = (float*)(ws + 1413376);        //    3,072 B  (total 1,416,448)

    k_norm<<<dim3(BN), dim3(64), 0, stream>>>(emb, xh, xl);
    k_meta<<<dim3(1), dim3(256), 0, stream>>>(labels, w, term0, pfrag);
    k_sim<<<dim3(6, 6), dim3(256), 0, stream>>>(xh, xl, sim);
    k_main<<<dim3(BN * 2), dim3(256), 0, stream>>>(sim, labels, w, pfrag, parts);
    k_final<<<dim3(1), dim3(64), 0, stream>>>(parts, term0, out);
}